// Round 10
// baseline (275.862 us; speedup 1.0000x reference)
//
#include <hip/hip_runtime.h>
#include <math.h>

// ---------------------------------------------------------------------------
// SimpleSelfAttention  B=4 S=2048 D=1024  fp32
// Round 18 (from R17 @ 245.7us):
//  - qkv_fused: pipelined plane reads — a+bQ+bK issued, counted lgkmcnt(4)
//    gates Q-MFMAs (bK in flight), bV issued under K-MFMAs, lgkm(0)+barrier
//    only before V cluster. Kills 4 of 6 DS-latency walls per K-tile.
//  - pv: split-K 8-wave core — 4 positions x 2 k-slices, wave tile 128x64
//    (the 41%-measured scores geometry), grid stays 256 = 1 round; split-K
//    partials reduced via LDS (reuses the staging buffers post-loop).
//  - scores (256x256 8-wave, 41%) and prep unchanged.
// ---------------------------------------------------------------------------

typedef _Float16 f16;
typedef _Float16 f16x8 __attribute__((ext_vector_type(8)));
typedef _Float16 f16x4 __attribute__((ext_vector_type(4)));
typedef float f32x4 __attribute__((ext_vector_type(4)));

__device__ __forceinline__ void glds16(const void* g, const void* l) {
    __builtin_amdgcn_global_load_lds(
        (const __attribute__((address_space(1))) void*)g,
        (__attribute__((address_space(3))) void*)l, 16, 0, 0);
}

#define VMCNT(n)  asm volatile("s_waitcnt vmcnt(" #n ")" ::: "memory")
#define LGKM(n)   asm volatile("s_waitcnt lgkmcnt(" #n ")" ::: "memory")
#define BARRIER() asm volatile("s_barrier" ::: "memory")
#define SCHEDB()  __builtin_amdgcn_sched_barrier(0)

// fused prep: fp32->fp16 for x (blocks [0,8192)), W planes (blocks [8192,11264)),
// zero sums (blocks [0,8))
__global__ __launch_bounds__(256) void prep_kernel(
    const float* __restrict__ x,
    const float* __restrict__ Wq, const float* __restrict__ Wk,
    const float* __restrict__ Wv,
    f16* __restrict__ xh, f16* __restrict__ Wh3, float* __restrict__ sums)
{
    const int bid = blockIdx.x, tid = threadIdx.x;
    if (bid < 8) {
        float4 z = {0.f, 0.f, 0.f, 0.f};
        ((float4*)sums)[bid * 256 + tid] = z;     // 8*256*4 = 8192 floats
    }
    if (bid < 8192) {
        const int i = bid * 256 + tid;
        float4 v = ((const float4*)x)[i];
        f16x4 h = { (f16)v.x, (f16)v.y, (f16)v.z, (f16)v.w };
        ((f16x4*)xh)[i] = h;
    } else {
        const int wid   = bid - 8192;             // 0..3071
        const int plane = wid >> 10;              // 0..2
        const int i     = (wid & 1023) * 256 + tid;
        const float* src = (plane == 0) ? Wq : (plane == 1) ? Wk : Wv;
        float4 v = ((const float4*)src)[i];
        f16x4 h = { (f16)v.x, (f16)v.y, (f16)v.z, (f16)v.w };
        ((f16x4*)(Wh3 + (size_t)plane * 1024 * 1024))[i] = h;
    }
}

// ---------------------------------------------------------------------------
// Fused QKV kernel: one block computes Q/K/V 256x128 tiles sharing the A
// stage/reads. 8 waves 4M x 2N (wave tile 64x64 per plane). BK=64, 2-deep,
// counted vmcnt(10). LDS: 2 x (A 256x64 = 32KB + B 384x64 = 48KB) = 160KB.
// Plane reads pipelined with counted lgkmcnt(4) (see header comment).
// ---------------------------------------------------------------------------
__global__ __launch_bounds__(512, 2) void qkv_fused_kernel(
    const f16* __restrict__ xh, const f16* __restrict__ Wh3,
    const float* __restrict__ bq, const float* __restrict__ bk,
    const float* __restrict__ bv,
    f16* __restrict__ Qh, f16* __restrict__ Kh, f16* __restrict__ Vt)
{
    extern __shared__ __align__(16) f16 smem[];
    const int bx = blockIdx.x >> 5;     // 0..7  -> n0
    const int by = blockIdx.x & 31;     // 0..31 -> m0
    const int m0 = by * 256;
    const int n0 = bx * 128;

    const int tid  = threadIdx.x;
    const int lane = tid & 63;
    const int w    = tid >> 6;          // 0..7
    const int wr   = w >> 1;            // 0..3 : wave row (64 rows)
    const int wc   = w & 1;             // 0..1 : wave col (64 cols)
    const int lr   = lane & 15;
    const int kq   = lane >> 4;

    const int rl = lane >> 3;           // staging row within 8-row group
    const int ch = (lane & 7) ^ rl;     // source k-chunk for this slot

    unsigned oA[4];
    #pragma unroll
    for (int p = 0; p < 4; ++p)
        oA[p] = (unsigned)((m0 + p * 64 + w * 8 + rl) * 1024 + ch * 8);
    unsigned oB[6];
    #pragma unroll
    for (int p = 0; p < 6; ++p) {
        const int g  = w * 48 + p * 8;          // concat row base (mult of 8)
        const int pl = g >> 7;                  // plane 0..2
        const int rp = g & 127;                 // row in plane
        oB[p] = (unsigned)(pl * 1048576 + (n0 + rp + rl) * 1024 + ch * 8);
    }

    f16* sA0 = smem;                f16* sA1 = smem + 16384;
    f16* sB0 = smem + 32768;        f16* sB1 = smem + 32768 + 24576;

    #define STAGEF(kofs, dA, dB) do {                                         \
        _Pragma("unroll")                                                     \
        for (int p = 0; p < 4; ++p)                                           \
            glds16(xh + oA[p] + (kofs), (dA) + w * 512 + p * 4096);           \
        _Pragma("unroll")                                                     \
        for (int p = 0; p < 6; ++p)                                           \
            glds16(Wh3 + oB[p] + (kofs), (dB) + w * 3072 + p * 512);          \
    } while (0)

    f32x4 aQ[4][4], aK[4][4], aV[4][4];
    #pragma unroll
    for (int i = 0; i < 4; ++i)
        #pragma unroll
        for (int j = 0; j < 4; ++j) {
            aQ[i][j] = (f32x4){0.f, 0.f, 0.f, 0.f};
            aK[i][j] = (f32x4){0.f, 0.f, 0.f, 0.f};
            aV[i][j] = (f32x4){0.f, 0.f, 0.f, 0.f};
        }

    STAGEF(0, sA0, sB0);                // tile 0 (10 loads)
    f16* curA = sA0; f16* curB = sB0;
    f16* othA = sA1; f16* othB = sB1;

    for (int t = 0; t < 16; ++t) {
        if (t < 15) { STAGEF((t + 1) * 64, othA, othB); VMCNT(10); }
        else        { VMCNT(0); }
        BARRIER();                      // tile t collectively ready

        #pragma unroll
        for (int kk = 0; kk < 2; ++kk) {
            const int c = kk * 4 + kq;
            f16x8 a[4], bQ[4], bK[4], bV[4];
            #pragma unroll
            for (int i = 0; i < 4; ++i) {
                const int ra = wr * 64 + i * 16 + lr;
                a[i] = *(const f16x8*)&curA[ra * 64 + ((c ^ (ra & 7)) * 8)];
            }
            #pragma unroll
            for (int j = 0; j < 4; ++j) {
                const int rb = wc * 64 + j * 16 + lr;
                bQ[j] = *(const f16x8*)&curB[rb * 64 + ((c ^ (rb & 7)) * 8)];
            }
            #pragma unroll
            for (int j = 0; j < 4; ++j) {
                const int rb = 128 + wc * 64 + j * 16 + lr;
                bK[j] = *(const f16x8*)&curB[rb * 64 + ((c ^ (rb & 7)) * 8)];
            }
            LGKM(4);                    // a + bQ retired; bK's 4 in flight
            SCHEDB();
            __builtin_amdgcn_s_setprio(1);
            #pragma unroll
            for (int i = 0; i < 4; ++i)
                #pragma unroll
                for (int j = 0; j < 4; ++j)
                    aQ[i][j] = __builtin_amdgcn_mfma_f32_16x16x32_f16(a[i], bQ[j], aQ[i][j], 0, 0, 0);
            __builtin_amdgcn_s_setprio(0);

            #pragma unroll
            for (int j = 0; j < 4; ++j) {
                const int rb = 256 + wc * 64 + j * 16 + lr;
                bV[j] = *(const f16x8*)&curB[rb * 64 + ((c ^ (rb & 7)) * 8)];
            }
            LGKM(4);                    // bK retired; bV's 4 in flight
            SCHEDB();
            __builtin_amdgcn_s_setprio(1);
            #pragma unroll
            for (int i = 0; i < 4; ++i)
                #pragma unroll
                for (int j = 0; j < 4; ++j)
                    aK[i][j] = __builtin_amdgcn_mfma_f32_16x16x32_f16(a[i], bK[j], aK[i][j], 0, 0, 0);
            __builtin_amdgcn_s_setprio(0);

            LGKM(0);                    // bV retired (all reads of cur done)
            if (kk == 1) BARRIER();     // cur reusable for next stage
            SCHEDB();
            __builtin_amdgcn_s_setprio(1);
            #pragma unroll
            for (int i = 0; i < 4; ++i)
                #pragma unroll
                for (int j = 0; j < 4; ++j)
                    aV[i][j] = __builtin_amdgcn_mfma_f32_16x16x32_f16(a[i], bV[j], aV[i][j], 0, 0, 0);
            __builtin_amdgcn_s_setprio(0);
        }

        f16* xp;
        xp = curA; curA = othA; othA = xp;
        xp = curB; curB = othB; othB = xp;
    }
    #undef STAGEF

    // ---- epilogue: Q (bias + 1/32 scale), K (bias), V transposed ----
    const int col  = lr;
    const int quad = kq;
    #pragma unroll
    for (int j = 0; j < 4; ++j) {
        const int gn = n0 + wc * 64 + j * 16 + col;
        const float bbq = bq[gn];
        const float bbk = bk[gn];
        #pragma unroll
        for (int i = 0; i < 4; ++i)
            #pragma unroll
            for (int r = 0; r < 4; ++r) {
                const int gm = m0 + wr * 64 + i * 16 + quad * 4 + r;
                Qh[(size_t)gm * 1024 + gn] = (f16)((aQ[i][j][r] + bbq) * 0.03125f);
                Kh[(size_t)gm * 1024 + gn] = (f16)(aK[i][j][r] + bbk);
            }
    }
    #pragma unroll
    for (int i = 0; i < 4; ++i) {
        const int gmb = m0 + wr * 64 + i * 16 + quad * 4;   // r=0 base (s)
        const int bb_ = gmb >> 11;
        const int s   = gmb & 2047;
        f16* vtb = Vt + (size_t)bb_ * 1024 * 2048;
        #pragma unroll
        for (int j = 0; j < 4; ++j) {
            const int gn = n0 + wc * 64 + j * 16 + col;
            const float bbv = bv[gn];
            f16x4 v = { (f16)(aV[i][j][0] + bbv), (f16)(aV[i][j][1] + bbv),
                        (f16)(aV[i][j][2] + bbv), (f16)(aV[i][j][3] + bbv) };
            *(f16x4*)&vtb[(size_t)gn * 2048 + s] = v;
        }
    }
}

// ---------------------------------------------------------------------------
// 256x256 NT fp16 MFMA core (scores): 8 waves 2M x 4N, wave tile 128x64,
// BK=64, 2-deep double buffer, counted vmcnt(8). LDS 128 KiB.
// ---------------------------------------------------------------------------
__device__ __forceinline__ void mfma_core8w(
    const f16* A, int lda,
    const f16* B, int ldb,
    int K, int m0, int n0, f16* sm, f32x4 (&acc)[8][4])
{
    const int tid  = threadIdx.x;
    const int lane = tid & 63;
    const int w    = tid >> 6;
    const int wr   = w >> 2;            // 0..1 : 128-row half
    const int wn   = w & 3;             // 0..3 : 64-col quarter
    const int lr   = lane & 15;
    const int kq   = lane >> 4;

    const int rl = lane >> 3;
    const int ch = (lane & 7) ^ rl;

    const f16* gA[4];
    #pragma unroll
    for (int p = 0; p < 4; ++p)
        gA[p] = A + (size_t)(m0 + p * 64 + w * 8 + rl) * lda + ch * 8;
    const f16* gB[4];
    #pragma unroll
    for (int p = 0; p < 4; ++p)
        gB[p] = B + (size_t)(n0 + p * 64 + w * 8 + rl) * ldb + ch * 8;

    const int NT = K >> 6;

    f16* sA0 = sm;              f16* sA1 = sm + 16384;
    f16* sB0 = sm + 32768;      f16* sB1 = sm + 49152;

    #define STAGE8(kofs, dA, dB) do {                                         \
        _Pragma("unroll")                                                     \
        for (int p = 0; p < 4; ++p)                                           \
            glds16(gA[p] + (kofs), (dA) + w * 512 + p * 4096);                \
        _Pragma("unroll")                                                     \
        for (int p = 0; p < 4; ++p)                                           \
            glds16(gB[p] + (kofs), (dB) + w * 512 + p * 4096);                \
    } while (0)

    STAGE8(0, sA0, sB0);

    f16* curA = sA0; f16* curB = sB0;
    f16* othA = sA1; f16* othB = sB1;

    for (int t = 0; t < NT; ++t) {
        if (t + 1 < NT) {
            STAGE8((t + 1) * 64, othA, othB);
            VMCNT(8);
        } else {
            VMCNT(0);
        }
        BARRIER();

        #pragma unroll
        for (int kk = 0; kk < 2; ++kk) {
            f16x8 a[8], b[4];
            const int c = kk * 4 + kq;
            #pragma unroll
            for (int i = 0; i < 8; ++i) {
                const int ra = wr * 128 + i * 16 + lr;
                a[i] = *(const f16x8*)&curA[ra * 64 + ((c ^ (ra & 7)) * 8)];
            }
            #pragma unroll
            for (int j = 0; j < 4; ++j) {
                const int rb = wn * 64 + j * 16 + lr;
                b[j] = *(const f16x8*)&curB[rb * 64 + ((c ^ (rb & 7)) * 8)];
            }
            LGKM(0);
            if (kk == 1) BARRIER();
            SCHEDB();
            __builtin_amdgcn_s_setprio(1);
            #pragma unroll
            for (int i = 0; i < 8; ++i)
                #pragma unroll
                for (int j = 0; j < 4; ++j)
                    acc[i][j] = __builtin_amdgcn_mfma_f32_16x16x32_f16(a[i], b[j], acc[i][j], 0, 0, 0);
            __builtin_amdgcn_s_setprio(0);
        }

        f16* x;
        x = curA; curA = othA; othA = x;
        x = curB; curB = othB; othB = x;
    }
    #undef STAGE8
}

// grid (8, 8, 4): 256x256 tiles, exactly 1 round. P = exp(QK^T) fp16,
// row sums accumulated into sums[b*S + row] via atomicAdd.
__global__ __launch_bounds__(512, 2) void scores_exp_kernel(
    const f16* __restrict__ Qh, const f16* __restrict__ Kh,
    f16* __restrict__ P, float* __restrict__ sums)
{
    extern __shared__ __align__(16) f16 smem[];
    const int b  = blockIdx.z;
    const int m0 = blockIdx.y * 256;
    const int n0 = blockIdx.x * 256;

    f32x4 acc[8][4];
    #pragma unroll
    for (int i = 0; i < 8; ++i)
        #pragma unroll
        for (int j = 0; j < 4; ++j) acc[i][j] = (f32x4){0.f, 0.f, 0.f, 0.f};

    const size_t ao = (size_t)b * 2048 * 1024;
    mfma_core8w(Qh + ao, 1024, Kh + ao, 1024, 1024, m0, n0, smem, acc);

    const int lane = threadIdx.x & 63;
    const int w    = threadIdx.x >> 6;
    const int wr = w >> 2, wn = w & 3;
    const int col  = lane & 15;
    const int quad = lane >> 4;
    f16* C = P + (size_t)b * 2048 * 2048;

    float rp[8][4];
    #pragma unroll
    for (int i = 0; i < 8; ++i)
        #pragma unroll
        for (int r = 0; r < 4; ++r) rp[i][r] = 0.0f;

    #pragma unroll
    for (int i = 0; i < 8; ++i)
        #pragma unroll
        for (int r = 0; r < 4; ++r) {
            const int gm = m0 + wr * 128 + i * 16 + quad * 4 + r;
            #pragma unroll
            for (int j = 0; j < 4; ++j) {
                const int gn = n0 + wn * 64 + j * 16 + col;
                const f16 p = (f16)__expf(acc[i][j][r]);
                C[(size_t)gm * 2048 + gn] = p;
                rp[i][r] += (float)p;   // sum what pv will actually read
            }
        }

    #pragma unroll
    for (int i = 0; i < 8; ++i)
        #pragma unroll
        for (int r = 0; r < 4; ++r) {
            float v = rp[i][r];
            v += __shfl_xor(v, 1);
            v += __shfl_xor(v, 2);
            v += __shfl_xor(v, 4);
            v += __shfl_xor(v, 8);
            rp[i][r] = v;
        }
    if (col == 0) {
        #pragma unroll
        for (int i = 0; i < 8; ++i)
            #pragma unroll
            for (int r = 0; r < 4; ++r) {
                const int row = m0 + wr * 128 + i * 16 + quad * 4 + r;
                atomicAdd(&sums[b * 2048 + row], rp[i][r]);
            }
    }
}

// ---------------------------------------------------------------------------
// pv: split-K 8-wave core. Tile 256x128, 4 positions (2M x 2N) x 2 k-slices,
// wave tile 128x64 at k-half ks. 3-deep staging (as core3), 12 ds_reads per
// wave per K-tile for 32 MFMAs. Split-K partials reduced via LDS post-loop.
// grid (8, 8, 4); out[r] = (P[r] @ Vt^T) / sums[r]
// ---------------------------------------------------------------------------
#define ABUF 16384      // f16 per A buffer (256*64)
#define BBUF 8192       // f16 per B buffer (128*64)
#define BOFF 49152      // f16 offset of B buffers (3*ABUF)

__global__ __launch_bounds__(512, 2) void pv_mfma_kernel(
    const f16* __restrict__ P, const f16* __restrict__ Vt,
    const float* __restrict__ sums, float* __restrict__ out)
{
    extern __shared__ __align__(16) f16 smem[];
    const int b  = blockIdx.z;
    const int m0 = blockIdx.y * 256;
    const int n0 = blockIdx.x * 128;

    const int tid  = threadIdx.x;
    const int lane = tid & 63;
    const int w    = tid >> 6;          // 0..7
    const int pos  = w >> 1;            // 0..3
    const int ks   = w & 1;             // k-slice
    const int wr2  = pos >> 1;          // 0..1 : 128-row half
    const int wc   = pos & 1;           // 0..1 : 64-col half
    const int lr   = lane & 15;
    const int kq   = lane >> 4;
    const int cb   = ks * 4 + kq;       // this wave's k-chunk base

    const int rl = lane >> 3;
    const int ch = (lane & 7) ^ rl;

    const f16* A = P  + (size_t)b * 2048 * 2048;
    const f16* B = Vt + (size_t)b * 1024 * 2048;

    const f16* gA[4];
    #pragma unroll
    for (int p = 0; p < 4; ++p)
        gA[p] = A + (size_t)(m0 + p * 64 + w * 8 + rl) * 2048 + ch * 8;
    const f16* gB[2];
    #pragma unroll
    for (int p = 0; p < 2; ++p)
        gB[p] = B + (size_t)(n0 + p * 64 + w * 8 + rl) * 2048 + ch * 8;

    f16* sA0 = smem;             f16* sB0 = smem + BOFF;
    f16* sA1 = smem + ABUF;      f16* sB1 = smem + BOFF + BBUF;
    f16* sA2 = smem + 2 * ABUF;  f16* sB2 = smem + BOFF + 2 * BBUF;

    #define STAGE(kofs, dA, dB) do {                                          \
        _Pragma("unroll")                                                     \
        for (int p = 0; p < 4; ++p)                                           \
            glds16(gA[p] + (kofs), (dA) + w * 512 + p * 4096);                \
        _Pragma("unroll")                                                     \
        for (int p = 0; p < 2; ++p)                                           \
            glds16(gB[p] + (kofs), (dB) + w * 512 + p * 4096);                \
    } while (0)

    f32x4 acc[8][4];
    #pragma unroll
    for (int i = 0; i < 8; ++i)
        #pragma unroll
        for (int j = 0; j < 4; ++j) acc[i][j] = (f32x4){0.f, 0.f, 0.f, 0.f};

    STAGE(0,  sA0, sB0);
    STAGE(64, sA1, sB1);

    int kst = 128;
    f16* curA = sA0; f16* curB = sB0;
    f16* nxtA = sA1; f16* nxtB = sB1;
    f16* farA = sA2; f16* farB = sB2;

    const int NT = 32;                  // K = 2048
    for (int t = 0; t < NT; ++t) {
        if (t + 2 < NT) {
            STAGE(kst, farA, farB);
            kst += 64;
            VMCNT(12);
        } else if (t + 1 < NT) {
            VMCNT(6);
        } else {
            VMCNT(0);
        }
        BARRIER();                      // tile t collectively ready

        f16x8 a[8], bb[4];
        #pragma unroll
        for (int i = 0; i < 8; ++i) {
            const int ra = wr2 * 128 + i * 16 + lr;
            a[i] = *(const f16x8*)&curA[ra * 64 + ((cb ^ (ra & 7)) * 8)];
        }
        #pragma unroll
        for (int j = 0; j < 4; ++j) {
            const int rb = wc * 64 + j * 16 + lr;
            bb[j] = *(const f16x8*)&curB[rb * 64 + ((cb ^ (rb & 7)) * 8)];
        }
        LGKM(0);                        // my 12 reads retired
        BARRIER();                      // collective: cur reusable
        SCHEDB();
        __builtin_amdgcn_s_setprio(1);
        #pragma unroll
        for (int i = 0; i < 8; ++i)
            #pragma unroll
            for (int j = 0; j < 4; ++j)
                acc[i][j] = __builtin_amdgcn_mfma_f32_16x16x32_f16(a[i], bb[j], acc[i][j], 0, 0, 0);
        __builtin_amdgcn_s_setprio(0);

        f16* tA = curA; f16* tB = curB;
        curA = nxtA; curB = nxtB;
        nxtA = farA; nxtB = farB;
        farA = tA;   farB = tB;
    }
    #undef STAGE

    // ---- split-K reduction via LDS (staging buffers dead) ----
    float* red = (float*)smem;          // 4 pos x 8192 f32 = 128 KiB
    if (ks == 1) {
        #pragma unroll
        for (int i = 0; i < 8; ++i)
            #pragma unroll
            for (int j = 0; j < 4; ++j)
                *(f32x4*)&red[(size_t)pos * 8192 + ((i * 4 + j) * 64 + lane) * 4] = acc[i][j];
        LGKM(0);
    }
    BARRIER();

    if (ks == 0) {
        float* C = out + (size_t)b * 2048 * 1024;
        #pragma unroll
        for (int i = 0; i < 8; ++i) {
            #pragma unroll
            for (int j = 0; j < 4; ++j) {
                f32x4 r4 = *(const f32x4*)&red[(size_t)pos * 8192 + ((i * 4 + j) * 64 + lane) * 4];
                acc[i][j] += r4;
            }
            #pragma unroll
            for (int r = 0; r < 4; ++r) {
                const int grow = m0 + wr2 * 128 + i * 16 + kq * 4 + r;
                const float inv = 1.0f / sums[b * 2048 + grow];
                #pragma unroll
                for (int j = 0; j < 4; ++j) {
                    const int gn = n0 + wc * 64 + j * 16 + lr;
                    C[(size_t)grow * 1024 + gn] = acc[i][j][r] * inv;
                }
            }
        }
    }
}

// ===========================================================================
extern "C" void kernel_launch(void* const* d_in, const int* in_sizes, int n_in,
                              void* d_out, int out_size, void* d_ws, size_t ws_size,
                              hipStream_t stream)
{
    (void)in_sizes; (void)n_in; (void)out_size; (void)ws_size;
    const int Bn = 4, S = 2048, D = 1024;
    const float* x  = (const float*)d_in[0];
    const float* Wq = (const float*)d_in[1];
    const float* bq = (const float*)d_in[2];
    const float* Wk = (const float*)d_in[3];
    const float* bk = (const float*)d_in[4];
    const float* Wv = (const float*)d_in[5];
    const float* bv = (const float*)d_in[6];
    float* out = (float*)d_out;

    const size_t MB = 1024 * 1024;
    char* w = (char*)d_ws;
    // [0..16)  xh   — dead after qkv   \
    // [16..22) Wh3  — dead after qkv    > P (32 MiB) aliases [0..38)
    // [22..38) (free)                  /
    // [38..54) Qh   [54..70) Kh   [70..86) Vt   [86..87) sums
    f16*   xh   = (f16*)(w + 0 * MB);
    f16*   Wh3  = (f16*)(w + 16 * MB);
    f16*   Qh   = (f16*)(w + 38 * MB);
    f16*   Kh   = (f16*)(w + 54 * MB);
    f16*   Vt   = (f16*)(w + 70 * MB);
    float* sums = (float*)(w + 86 * MB);
    f16*   P    = (f16*)(w + 0 * MB);

    static bool attr_set = false;
    if (!attr_set) {
        (void)hipFuncSetAttribute(reinterpret_cast<const void*>(qkv_fused_kernel),
                            hipFuncAttributeMaxDynamicSharedMemorySize, 163840);
        (void)hipFuncSetAttribute(reinterpret_cast<const void*>(scores_exp_kernel),
                            hipFuncAttributeMaxDynamicSharedMemorySize, 131072);
        (void)hipFuncSetAttribute(reinterpret_cast<const void*>(pv_mfma_kernel),
                            hipFuncAttributeMaxDynamicSharedMemorySize, 147456);
        attr_set = true;
    }

    // 1) fused prep: fp32->fp16 x + W planes, zero row sums
    prep_kernel<<<dim3(11264), 256, 0, stream>>>(x, Wq, Wk, Wv, xh, Wh3, sums);

    // 2) QKV fused: one block per (m,n) computes Q, K, V^T tiles
    qkv_fused_kernel<<<dim3(256), 512, 163840, stream>>>(
        xh, Wh3, bq, bk, bv, Qh, Kh, Vt);

    // 3) attention: exp-scores 256x256 (+row sums) -> PV split-K w/ normalize
    scores_exp_kernel<<<dim3(S / 256, S / 256, Bn), 512, 131072, stream>>>(
        Qh, Kh, P, sums);
    pv_mfma_kernel<<<dim3(D / 128, S / 256, Bn), 512, 147456, stream>>>(
        P, Vt, sums, out);
}